// Round 6
// baseline (166.375 us; speedup 1.0000x reference)
//
#include <hip/hip_runtime.h>

#define IMG_SIZE 256
#define NPIX (IMG_SIZE * IMG_SIZE)
#define KSEL 5
#define BS 8
#define LL 64
#define LUSED 63                 // row l=63's top-k is discarded by the roll
#define NTHREADS 256
#define RROWS 4                  // rows (same image) per block; 64 = 16*4
#define NGRPI 16                 // row-groups per image (computes unused l=63: +1.6%, uniform geometry)
#define SPLIT 8                  // chunks per image
#define CHUNK_V4 (NPIX / 4 / SPLIT)    // 2048 float4
#define ITERS (CHUNK_V4 / NTHREADS)    // 8
#define NBLOCKS (BS * NGRPI * SPLIT)   // 1024
#define CAP 16                   // candidate slots per (row, chunk) — expect ~5-6
#define FBIG 3.402823466e38f
#define UINF 0xFFFFFFFFFFFFFFFFULL
#define KEYS_ROWS (BS * LL)      // 512 storage rows
#define COUNTER_OFF (KEYS_ROWS * SPLIT * KSEL * 8)   // 163840 B

typedef unsigned long long ull;

__device__ __forceinline__ float dist3(float r0, float r1, float r2,
                                       float c0, float c1, float c2) {
    // Match numpy f32 exactly: no FMA contraction, ((d0^2+d1^2)+d2^2).
    float d0 = __fsub_rn(r0, c0);
    float d1 = __fsub_rn(r1, c1);
    float d2 = __fsub_rn(r2, c2);
    return __fadd_rn(__fadd_rn(__fmul_rn(d0, d0), __fmul_rn(d1, d1)),
                     __fmul_rn(d2, d2));
}

// Sorted-insert of value k into ascending 5-list: 1 v_min + 4 v_med3, depth-1.
__device__ __forceinline__ void vins(float l[KSEL], float k) {
    float b0 = fminf(l[0], k);
    float b1 = __builtin_amdgcn_fmed3f(l[0], l[1], k);
    float b2 = __builtin_amdgcn_fmed3f(l[1], l[2], k);
    float b3 = __builtin_amdgcn_fmed3f(l[2], l[3], k);
    float b4 = __builtin_amdgcn_fmed3f(l[3], l[4], k);
    l[0] = b0; l[1] = b1; l[2] = b2; l[3] = b3; l[4] = b4;
}

// Merge two ascending f32 5-lists, keep smallest 5 in a.
__device__ __forceinline__ void merge5f(float* a, const float* b) {
    float out[KSEL];
    int ia = 0, ib = 0;
    #pragma unroll
    for (int j = 0; j < KSEL; ++j) {
        const float va = a[ia], vb = b[ib];
        const bool ta = va <= vb;
        out[j] = ta ? va : vb;
        ia += ta ? 1 : 0;
        ib += ta ? 0 : 1;
    }
    #pragma unroll
    for (int j = 0; j < KSEL; ++j) a[j] = out[j];
}

// Exact lexicographic (dist,idx) insert: u64 compare + selects.
__device__ __forceinline__ void uins(ull l[KSEL], ull k) {
    #pragma unroll
    for (int j = 0; j < KSEL; ++j) {
        const ull a = l[j];
        const bool lt = k < a;
        l[j] = lt ? k : a;
        k    = lt ? a : k;
    }
}

__device__ __forceinline__ ull pack_key(float d, int pix) {
    // d >= 0 -> uint bit order == float order; low bits = pixel idx -> jax
    // top_k lower-index-first tie-break.
    return ((ull)__float_as_uint(d) << 32) | (unsigned int)pix;
}

__global__ __launch_bounds__(NTHREADS)
void cc_loss_kernel(const float* __restrict__ preds,
                    const float* __restrict__ imgs,
                    ull* __restrict__ keys,
                    int* __restrict__ counter,
                    float* __restrict__ out) {
    const int bx = blockIdx.x;
    const int chunk = bx & (SPLIT - 1);
    const int grp = bx >> 3;
    const int b = grp >> 4;              // image
    const int g = grp & 15;              // row-group
    const int t = threadIdx.x;

    const float* imgb = imgs + (size_t)b * 3 * NPIX;

    // Pooled centers for the 4 rows this block serves.
    float c0[RROWS], c1[RROWS], c2[RROWS];
    #pragma unroll
    for (int r = 0; r < RROWS; ++r) {
        const int l = g * RROWS + r;
        // Scrambled pooled indexing: flat i = l*bs + b; pos from preds[i//64, i%64].
        const int i = l * BS + b;
        const int pb = i >> 6;
        const int pl = i & 63;
        const float px = preds[pb * (LL * 8) + pl * 8 + 0];
        const float py = preds[pb * (LL * 8) + pl * 8 + 1];
        const float cx = __fsub_rn(__fmul_rn(px, 256.0f), 0.5f);
        const float cy = __fsub_rn(__fmul_rn(py, 256.0f), 0.5f);
        const int ix = (int)rintf(cx);   // round half to even == jnp.rint
        const int iy = (int)rintf(cy);
        const bool valid = (ix >= 0) && (ix < IMG_SIZE) && (iy >= 0) && (iy < IMG_SIZE);
        const int ixc = min(max(ix, 0), IMG_SIZE - 1);
        const int iyc = min(max(iy, 0), IMG_SIZE - 1);
        const float vmul = valid ? 1.0f : 0.0f;
        c0[r] = imgb[0 * NPIX + iyc * IMG_SIZE + ixc] * vmul;
        c1[r] = imgb[1 * NPIX + iyc * IMG_SIZE + ixc] * vmul;
        c2[r] = imgb[2 * NPIX + iyc * IMG_SIZE + ixc] * vmul;
    }

    const float4* p0 = (const float4*)(imgb + 0 * NPIX);
    const float4* p1 = (const float4*)(imgb + 1 * NPIX);
    const float4* p2 = (const float4*)(imgb + 2 * NPIX);
    const int vbase = chunk * CHUNK_V4;

    // ---- Pass 1: per-thread 5 smallest VALUES per row.
    float lad[RROWS][KSEL];
    #pragma unroll
    for (int r = 0; r < RROWS; ++r)
        #pragma unroll
        for (int j = 0; j < KSEL; ++j) lad[r][j] = FBIG;

    #pragma unroll 2
    for (int it = 0; it < ITERS; ++it) {
        const int v = vbase + it * NTHREADS + t;
        const float4 r0 = p0[v];
        const float4 r1 = p1[v];
        const float4 r2 = p2[v];
        #pragma unroll
        for (int r = 0; r < RROWS; ++r) {
            vins(lad[r], dist3(r0.x, r1.x, r2.x, c0[r], c1[r], c2[r]));
            vins(lad[r], dist3(r0.y, r1.y, r2.y, c0[r], c1[r], c2[r]));
            vins(lad[r], dist3(r0.z, r1.z, r2.z, c0[r], c1[r], c2[r]));
            vins(lad[r], dist3(r0.w, r1.w, r2.w, c0[r], c1[r], c2[r]));
        }
    }

    // ---- Block-level exact v5 per row: LDS merge tree (R2-style), all rows per level.
    __shared__ float skv[RROWS][NTHREADS * KSEL];   // 20 KB
    #pragma unroll
    for (int r = 0; r < RROWS; ++r)
        #pragma unroll
        for (int j = 0; j < KSEL; ++j) skv[r][t * KSEL + j] = lad[r][j];
    __syncthreads();
    for (int s = NTHREADS / 2; s > 0; s >>= 1) {
        if (t < s) {
            #pragma unroll
            for (int r = 0; r < RROWS; ++r) {
                float a[KSEL], bb[KSEL];
                #pragma unroll
                for (int j = 0; j < KSEL; ++j) { a[j] = skv[r][t * KSEL + j]; bb[j] = skv[r][(t + s) * KSEL + j]; }
                merge5f(a, bb);
                #pragma unroll
                for (int j = 0; j < KSEL; ++j) skv[r][t * KSEL + j] = a[j];
            }
        }
        __syncthreads();
    }
    float T[RROWS];
    #pragma unroll
    for (int r = 0; r < RROWS; ++r) T[r] = skv[r][4];   // exact block-chunk v5 (broadcast read)

    __shared__ ull cand[RROWS][CAP];
    __shared__ int cnt[RROWS];
    if (t < RROWS) cnt[t] = 0;
    __syncthreads();

    // ---- Pass 2: re-scan; capture all pixels with d <= v5 (exact, ties kept).
    #pragma unroll 2
    for (int it = 0; it < ITERS; ++it) {
        const int v = vbase + it * NTHREADS + t;
        const float4 r0 = p0[v];
        const float4 r1 = p1[v];
        const float4 r2 = p2[v];
        const int base = v * 4;
        #pragma unroll
        for (int r = 0; r < RROWS; ++r) {
            const float d0 = dist3(r0.x, r1.x, r2.x, c0[r], c1[r], c2[r]);
            const float d1 = dist3(r0.y, r1.y, r2.y, c0[r], c1[r], c2[r]);
            const float d2 = dist3(r0.z, r1.z, r2.z, c0[r], c1[r], c2[r]);
            const float d3 = dist3(r0.w, r1.w, r2.w, c0[r], c1[r], c2[r]);
            const float vv = T[r];
            if (fminf(fminf(d0, d1), fminf(d2, d3)) <= vv) {   // execz-skipped mostly
                if (d0 <= vv) { int s = atomicAdd(&cnt[r], 1); if (s < CAP) cand[r][s] = pack_key(d0, base + 0); }
                if (d1 <= vv) { int s = atomicAdd(&cnt[r], 1); if (s < CAP) cand[r][s] = pack_key(d1, base + 1); }
                if (d2 <= vv) { int s = atomicAdd(&cnt[r], 1); if (s < CAP) cand[r][s] = pack_key(d2, base + 2); }
                if (d3 <= vv) { int s = atomicAdd(&cnt[r], 1); if (s < CAP) cand[r][s] = pack_key(d3, base + 3); }
            }
        }
    }
    __syncthreads();

    // ---- Exact lexicographic top-5 over the few candidates; write to global.
    if (t < RROWS) {
        const int n = min(cnt[t], CAP);
        ull m[KSEL];
        #pragma unroll
        for (int j = 0; j < KSEL; ++j) m[j] = UINF;
        for (int i2 = 0; i2 < n; ++i2) uins(m, cand[t][i2]);
        const int row = b * LL + g * RROWS + t;
        #pragma unroll
        for (int j = 0; j < KSEL; ++j)
            keys[((size_t)row * SPLIT + chunk) * KSEL + j] = m[j];
    }

    // ---- Last-block epilogue.
    __shared__ int is_last;
    __threadfence();
    if (t == 0) {
        const int prev = atomicAdd(counter, 1);
        is_last = (prev == NBLOCKS - 1);
    }
    __syncthreads();
    if (!is_last) return;
    __threadfence();

    float acc = 0.0f;
    for (int rr = t; rr < BS * LUSED; rr += NTHREADS) {
        const int rb = rr / LUSED;
        const int rl = rr % LUSED;          // storage row rl feeds loss row rl+1
        const int srow = rb * LL + rl;
        ull m[KSEL];
        #pragma unroll
        for (int j = 0; j < KSEL; ++j) m[j] = UINF;
        #pragma unroll 1
        for (int c = 0; c < SPLIT; ++c)
            #pragma unroll
            for (int k = 0; k < KSEL; ++k)
                uins(m, keys[((size_t)srow * SPLIT + c) * KSEL + k]);
        const int lp = rl + 1;
        const float qx = preds[rb * (LL * 8) + lp * 8 + 0];
        const float qy = preds[rb * (LL * 8) + lp * 8 + 1];
        float best = FBIG;
        #pragma unroll
        for (int k = 0; k < KSEL; ++k) {
            const int idx = (int)(m[k] & 0xFFFFFFFFULL);
            const float tx = (float)(idx & 255) * (1.0f / 256.0f);   // exact /256
            const float ty = (float)(idx >> 8) * (1.0f / 256.0f);
            const float dx = __fsub_rn(qx, tx);
            const float dy = __fsub_rn(qy, ty);
            const float dist = __fadd_rn(__fmul_rn(dx, dx), __fmul_rn(dy, dy));
            best = dist < best ? dist : best;   // first-min tie semantics
        }
        acc += best;
    }

    __shared__ float red[NTHREADS];
    red[t] = acc;
    __syncthreads();
    for (int s = NTHREADS / 2; s > 0; s >>= 1) {
        if (t < s) red[t] += red[t + s];
        __syncthreads();
    }
    if (t == 0) {
        out[0] = red[0] / (float)(BS * (LL - 1));
    }
}

extern "C" void kernel_launch(void* const* d_in, const int* in_sizes, int n_in,
                              void* d_out, int out_size, void* d_ws, size_t ws_size,
                              hipStream_t stream) {
    const float* preds = (const float*)d_in[0];   // (8, 64, 8) f32
    const float* imgs  = (const float*)d_in[1];   // (8, 3, 256, 256) f32
    float* out = (float*)d_out;                   // scalar f32
    ull* keys = (ull*)d_ws;                       // 512*8*5 u64 = 163840 B
    int* counter = (int*)((char*)d_ws + COUNTER_OFF);

    // d_ws is re-poisoned to 0xAA before every launch: zero the arrival counter.
    hipMemsetAsync(counter, 0, sizeof(int), stream);
    cc_loss_kernel<<<dim3(NBLOCKS), dim3(NTHREADS), 0, stream>>>(preds, imgs, keys, counter, out);
}

// Round 7
// 154.384 us; speedup vs baseline: 1.0777x; 1.0777x over previous
//
#include <hip/hip_runtime.h>

#define IMG_SIZE 256
#define NPIX (IMG_SIZE * IMG_SIZE)
#define KSEL 5
#define BS 8
#define LL 64
#define LUSED 63                  // row l=63's top-k is discarded by the roll
#define NTHREADS 256
#define RROWS 2                   // rows per block (l = 2g, 2g+1); l=63 computed but unused
#define NPAIR 32                  // row-pairs per image
#define SPLIT 4                   // chunks per image
#define CHUNK_V4 (NPIX / 4 / SPLIT)    // 4096 float4
#define ITERS (CHUNK_V4 / NTHREADS)    // 16 — deep loop (R2-style latency hiding)
#define NBLOCKS (BS * NPAIR * SPLIT)   // 1024 = 4 blocks/CU
#define CAP 24                    // candidate slots per (row, chunk); expect ~5-6
#define FBIG 3.402823466e38f
#define UINF 0xFFFFFFFFFFFFFFFFULL
#define KEYS_BYTES (BS * LL * SPLIT * KSEL * 8)   // 81920
#define COUNTER_OFF KEYS_BYTES

typedef unsigned long long ull;

// Exact numpy-rounded distance (used ONLY on the few candidates).
__device__ __forceinline__ float dist3_exact(float r0, float r1, float r2,
                                             float c0, float c1, float c2) {
    float d0 = __fsub_rn(r0, c0);
    float d1 = __fsub_rn(r1, c1);
    float d2 = __fsub_rn(r2, c2);
    return __fadd_rn(__fadd_rn(__fmul_rn(d0, d0), __fmul_rn(d1, d1)),
                     __fmul_rn(d2, d2));
}

// Fast approx distance for selection: same subs, fused accumulation.
// |approx - exact| <= ~3 ulp(dist) — covered by the capture slack.
__device__ __forceinline__ float dist3_fast(float r0, float r1, float r2,
                                            float c0, float c1, float c2) {
    float d0 = __fsub_rn(r0, c0);
    float d1 = __fsub_rn(r1, c1);
    float d2 = __fsub_rn(r2, c2);
    return fmaf(d0, d0, fmaf(d1, d1, __fmul_rn(d2, d2)));
}

// Sorted-insert of value k into ascending 5-list: 1 v_min + 4 v_med3, depth-1.
__device__ __forceinline__ void vins(float l[KSEL], float k) {
    float b0 = fminf(l[0], k);
    float b1 = __builtin_amdgcn_fmed3f(l[0], l[1], k);
    float b2 = __builtin_amdgcn_fmed3f(l[1], l[2], k);
    float b3 = __builtin_amdgcn_fmed3f(l[2], l[3], k);
    float b4 = __builtin_amdgcn_fmed3f(l[3], l[4], k);
    l[0] = b0; l[1] = b1; l[2] = b2; l[3] = b3; l[4] = b4;
}

// Exact lexicographic (dist,idx) insert: u64 compare + selects (epilogue only).
__device__ __forceinline__ void uins(ull l[KSEL], ull k) {
    #pragma unroll
    for (int j = 0; j < KSEL; ++j) {
        const ull a = l[j];
        const bool lt = k < a;
        l[j] = lt ? k : a;
        k    = lt ? a : k;
    }
}

__device__ __forceinline__ ull shfl_xor_u64(ull v, int m) {
    const int lo = __shfl_xor((int)(unsigned int)v, m, 64);
    const int hi = __shfl_xor((int)(unsigned int)(v >> 32), m, 64);
    return ((ull)(unsigned int)hi << 32) | (unsigned int)lo;
}

__global__ __launch_bounds__(NTHREADS)
void cc_loss_kernel(const float* __restrict__ preds,
                    const float* __restrict__ imgs,
                    ull* __restrict__ keys,
                    int* __restrict__ counter,
                    float* __restrict__ out) {
    const int bx = blockIdx.x;
    const int b = bx & 7;                 // image — bx%8 pins image to one XCD (L2 locality)
    const int rem = bx >> 3;
    const int chunk = rem & (SPLIT - 1);
    const int pair = rem >> 2;            // 0..31
    const int t = threadIdx.x;
    const int wv = t >> 6;
    const int lane = t & 63;

    const float* imgb = imgs + (size_t)b * 3 * NPIX;

    // Pooled centers for the 2 rows this block serves (redundant per-thread).
    float c0[RROWS], c1[RROWS], c2[RROWS];
    #pragma unroll
    for (int r = 0; r < RROWS; ++r) {
        const int l = pair * RROWS + r;
        // Scrambled pooled indexing: flat i = l*bs + b; pos from preds[i//64, i%64].
        const int i = l * BS + b;
        const int pb = i >> 6;
        const int pl = i & 63;
        const float px = preds[pb * (LL * 8) + pl * 8 + 0];
        const float py = preds[pb * (LL * 8) + pl * 8 + 1];
        const float cx = __fsub_rn(__fmul_rn(px, 256.0f), 0.5f);
        const float cy = __fsub_rn(__fmul_rn(py, 256.0f), 0.5f);
        const int ix = (int)rintf(cx);    // round half to even == jnp.rint
        const int iy = (int)rintf(cy);
        const bool valid = (ix >= 0) && (ix < IMG_SIZE) && (iy >= 0) && (iy < IMG_SIZE);
        const int ixc = min(max(ix, 0), IMG_SIZE - 1);
        const int iyc = min(max(iy, 0), IMG_SIZE - 1);
        const float vmul = valid ? 1.0f : 0.0f;
        c0[r] = imgb[0 * NPIX + iyc * IMG_SIZE + ixc] * vmul;
        c1[r] = imgb[1 * NPIX + iyc * IMG_SIZE + ixc] * vmul;
        c2[r] = imgb[2 * NPIX + iyc * IMG_SIZE + ixc] * vmul;
    }

    const float4* p0 = (const float4*)(imgb + 0 * NPIX);
    const float4* p1 = (const float4*)(imgb + 1 * NPIX);
    const float4* p2 = (const float4*)(imgb + 2 * NPIX);
    const int vbase = chunk * CHUNK_V4;

    // ---- Pass 1: per-thread 5 smallest approx VALUES per row (deep 16-iter loop).
    float lad[RROWS][KSEL];
    #pragma unroll
    for (int r = 0; r < RROWS; ++r)
        #pragma unroll
        for (int j = 0; j < KSEL; ++j) lad[r][j] = FBIG;

    #pragma unroll 2
    for (int it = 0; it < ITERS; ++it) {
        const int v = vbase + it * NTHREADS + t;
        const float4 r0 = p0[v];
        const float4 r1 = p1[v];
        const float4 r2 = p2[v];
        #pragma unroll
        for (int r = 0; r < RROWS; ++r) {
            vins(lad[r], dist3_fast(r0.x, r1.x, r2.x, c0[r], c1[r], c2[r]));
            vins(lad[r], dist3_fast(r0.y, r1.y, r2.y, c0[r], c1[r], c2[r]));
            vins(lad[r], dist3_fast(r0.z, r1.z, r2.z, c0[r], c1[r], c2[r]));
            vins(lad[r], dist3_fast(r0.w, r1.w, r2.w, c0[r], c1[r], c2[r]));
        }
    }

    // ---- Wave butterfly merge (6 shuffle rounds; no barriers).
    #pragma unroll
    for (int m = 1; m <= 32; m <<= 1) {
        #pragma unroll
        for (int r = 0; r < RROWS; ++r) {
            float o[KSEL];
            #pragma unroll
            for (int j = 0; j < KSEL; ++j) o[j] = __shfl_xor(lad[r][j], m, 64);
            #pragma unroll
            for (int j = 0; j < KSEL; ++j) vins(lad[r], o[j]);
        }
    }

    // ---- Cross-wave merge via tiny LDS; every thread derives the block v5.
    __shared__ float swl[4][RROWS][KSEL];        // 160 B
    __shared__ int cand[RROWS][CAP];             // pixel indices
    __shared__ int cnt[RROWS];
    if (lane == 0) {
        #pragma unroll
        for (int r = 0; r < RROWS; ++r)
            #pragma unroll
            for (int j = 0; j < KSEL; ++j) swl[wv][r][j] = lad[r][j];
    }
    if (t == 0) { cnt[0] = 0; cnt[1] = 0; }
    __syncthreads();

    float thr[RROWS];
    #pragma unroll
    for (int r = 0; r < RROWS; ++r) {
        float m5[KSEL];
        #pragma unroll
        for (int j = 0; j < KSEL; ++j) m5[j] = FBIG;
        #pragma unroll
        for (int w = 0; w < 4; ++w)
            #pragma unroll
            for (int j = 0; j < KSEL; ++j) vins(m5, swl[w][r][j]);
        // Capture slack >> 3-ulp fast-vs-exact gap; expected extra captures ~0.
        thr[r] = m5[4] * 1.001f + 1e-7f;
    }

    // ---- Pass 2: re-scan; capture pixel INDICES with fast dist <= thr.
    #pragma unroll 2
    for (int it = 0; it < ITERS; ++it) {
        const int v = vbase + it * NTHREADS + t;
        const float4 r0 = p0[v];
        const float4 r1 = p1[v];
        const float4 r2 = p2[v];
        const int base = v * 4;
        #pragma unroll
        for (int r = 0; r < RROWS; ++r) {
            const float d0 = dist3_fast(r0.x, r1.x, r2.x, c0[r], c1[r], c2[r]);
            const float d1 = dist3_fast(r0.y, r1.y, r2.y, c0[r], c1[r], c2[r]);
            const float d2 = dist3_fast(r0.z, r1.z, r2.z, c0[r], c1[r], c2[r]);
            const float d3 = dist3_fast(r0.w, r1.w, r2.w, c0[r], c1[r], c2[r]);
            const float vv = thr[r];
            if (fminf(fminf(d0, d1), fminf(d2, d3)) <= vv) {   // execz-skipped
                if (d0 <= vv) { int s = atomicAdd(&cnt[r], 1); if (s < CAP) cand[r][s] = base + 0; }
                if (d1 <= vv) { int s = atomicAdd(&cnt[r], 1); if (s < CAP) cand[r][s] = base + 1; }
                if (d2 <= vv) { int s = atomicAdd(&cnt[r], 1); if (s < CAP) cand[r][s] = base + 2; }
                if (d3 <= vv) { int s = atomicAdd(&cnt[r], 1); if (s < CAP) cand[r][s] = base + 3; }
            }
        }
    }
    __syncthreads();

    // ---- Exact top-5: wave r re-derives exact dists for its <=CAP candidates,
    // then 5 rounds of u64 butterfly-min (lexicographic (dist,idx), exact ties).
    if (wv < RROWS) {
        const int r = wv;
        const int n = min(cnt[r], CAP);
        ull key = UINF;
        if (lane < n) {
            const int idx = cand[r][lane];
            const float e0 = imgb[0 * NPIX + idx];
            const float e1 = imgb[1 * NPIX + idx];
            const float e2 = imgb[2 * NPIX + idx];
            const float dd = dist3_exact(e0, e1, e2, c0[r], c1[r], c2[r]);
            key = ((ull)__float_as_uint(dd) << 32) | (unsigned int)idx;
        }
        const int row = b * LL + pair * RROWS + r;
        ull* kout = &keys[((size_t)row * SPLIT + chunk) * KSEL];
        #pragma unroll
        for (int k = 0; k < KSEL; ++k) {
            ull red = key;
            #pragma unroll
            for (int m = 1; m <= 32; m <<= 1) {
                const ull o = shfl_xor_u64(red, m);
                red = (o < red) ? o : red;
            }
            if (lane == 0) kout[k] = red;
            key = (key == red) ? UINF : key;   // idx unique -> no double removal
        }
    }
    __syncthreads();            // drain wave 0/1 global writes before counter bump

    // ---- Last-block epilogue.
    __shared__ int is_last;
    __threadfence();
    if (t == 0) {
        const int prev = atomicAdd(counter, 1);
        is_last = (prev == NBLOCKS - 1);
    }
    __syncthreads();
    if (!is_last) return;
    __threadfence();

    float acc = 0.0f;
    for (int rr = t; rr < BS * LUSED; rr += NTHREADS) {
        const int rb = rr / LUSED;
        const int rl = rr % LUSED;          // storage row rl feeds loss row rl+1
        const int srow = rb * LL + rl;
        ull m[KSEL];
        #pragma unroll
        for (int j = 0; j < KSEL; ++j) m[j] = UINF;
        #pragma unroll 1
        for (int c = 0; c < SPLIT; ++c)
            #pragma unroll
            for (int k = 0; k < KSEL; ++k)
                uins(m, keys[((size_t)srow * SPLIT + c) * KSEL + k]);
        const int lp = rl + 1;
        const float qx = preds[rb * (LL * 8) + lp * 8 + 0];
        const float qy = preds[rb * (LL * 8) + lp * 8 + 1];
        float best = FBIG;
        #pragma unroll
        for (int k = 0; k < KSEL; ++k) {
            const int idx = (int)(m[k] & 0xFFFFFFFFULL);
            const float tx = (float)(idx & 255) * (1.0f / 256.0f);   // exact /256
            const float ty = (float)(idx >> 8) * (1.0f / 256.0f);
            const float dx = __fsub_rn(qx, tx);
            const float dy = __fsub_rn(qy, ty);
            const float dist = __fadd_rn(__fmul_rn(dx, dx), __fmul_rn(dy, dy));
            best = dist < best ? dist : best;   // first-min tie semantics
        }
        acc += best;
    }

    __shared__ float red[NTHREADS];
    red[t] = acc;
    __syncthreads();
    for (int s = NTHREADS / 2; s > 0; s >>= 1) {
        if (t < s) red[t] += red[t + s];
        __syncthreads();
    }
    if (t == 0) {
        out[0] = red[0] / (float)(BS * (LL - 1));
    }
}

extern "C" void kernel_launch(void* const* d_in, const int* in_sizes, int n_in,
                              void* d_out, int out_size, void* d_ws, size_t ws_size,
                              hipStream_t stream) {
    const float* preds = (const float*)d_in[0];   // (8, 64, 8) f32
    const float* imgs  = (const float*)d_in[1];   // (8, 3, 256, 256) f32
    float* out = (float*)d_out;                   // scalar f32
    ull* keys = (ull*)d_ws;                       // 512*4*5 u64 = 81920 B
    int* counter = (int*)((char*)d_ws + COUNTER_OFF);

    // d_ws is re-poisoned to 0xAA before every launch: zero the arrival counter.
    hipMemsetAsync(counter, 0, sizeof(int), stream);
    cc_loss_kernel<<<dim3(NBLOCKS), dim3(NTHREADS), 0, stream>>>(preds, imgs, keys, counter, out);
}